// Round 11
// baseline (548.793 us; speedup 1.0000x reference)
//
#include <hip/hip_runtime.h>

// LGCN encoder: out = (ego + A*ego + A^2*ego + A^3*ego) / 4
// Counting-sort CSR build + bf16 gather SpMM.
// SpMM: 8 lanes/row (16B/lane), edge loop unrolled x4 -> 32 gathers in flight/wave.

#define U_ROWS 100000
#define NROWS  150000
#define D      64
#define NNZ    3000000
#define NB     ((NROWS + 255) >> 8)   // 586 buckets of 256 rows

// ---------- stage 1a: bucket histogram (LDS-aggregated) ----------
__global__ void k_bhist(const int* __restrict__ rows, int* __restrict__ bcnt) {
    __shared__ int lds[NB];
    for (int i = threadIdx.x; i < NB; i += blockDim.x) lds[i] = 0;
    __syncthreads();
    int stride = gridDim.x * blockDim.x;
    for (int e = blockIdx.x * blockDim.x + threadIdx.x; e < NNZ; e += stride)
        atomicAdd(&lds[rows[e] >> 8], 1);
    __syncthreads();
    for (int i = threadIdx.x; i < NB; i += blockDim.x)
        if (lds[i]) atomicAdd(&bcnt[i], lds[i]);
}

// ---------- stage 1b: scan bucket counts -> bbase, init bfill ----------
__global__ void k_bscan(const int* __restrict__ bcnt,
                        int* __restrict__ bbase, int* __restrict__ bfill) {
    __shared__ int s[1024];
    int t = threadIdx.x;
    int c = (t < NB) ? bcnt[t] : 0;
    s[t] = c;
    __syncthreads();
    for (int off = 1; off < 1024; off <<= 1) {
        int v = (t >= off) ? s[t - off] : 0;
        __syncthreads();
        s[t] += v;
        __syncthreads();
    }
    if (t < NB) { int b = s[t] - c; bbase[t] = b; bfill[t] = b; }
    if (t == 0) bbase[NB] = NNZ;
}

// ---------- stage 2: partition edges into bucket streams ----------
// ebuf entry: {col | row_lo<<18, f32 bits of val}
#define P1B_T 512
#define P1B_E 8
__global__ void k_part(const int* __restrict__ rows, const int* __restrict__ cols,
                       const float* __restrict__ vals,
                       int* __restrict__ bfill, int2* __restrict__ ebuf) {
    __shared__ int cnt[NB];
    __shared__ int rbase[NB];
    for (int i = threadIdx.x; i < NB; i += P1B_T) cnt[i] = 0;
    __syncthreads();
    int base = blockIdx.x * (P1B_T * P1B_E);
    int bk[P1B_E], rk[P1B_E], rl[P1B_E];
#pragma unroll
    for (int k = 0; k < P1B_E; ++k) {
        int e = base + threadIdx.x + k * P1B_T;   // coalesced
        if (e < NNZ) {
            int r = rows[e];
            bk[k] = r >> 8; rl[k] = r & 255;
            rk[k] = atomicAdd(&cnt[bk[k]], 1);
        } else bk[k] = -1;
    }
    __syncthreads();
    for (int i = threadIdx.x; i < NB; i += P1B_T) {
        int c = cnt[i];
        rbase[i] = c ? atomicAdd(&bfill[i], c) : 0;
    }
    __syncthreads();
#pragma unroll
    for (int k = 0; k < P1B_E; ++k) {
        if (bk[k] >= 0) {
            int e = base + threadIdx.x + k * P1B_T;
            ebuf[rbase[bk[k]] + rk[k]] =
                make_int2(cols[e] | (rl[k] << 18), __float_as_int(vals[e]));
        }
    }
}

// ---------- stage 3: per-bucket fine CSR, IN-PLACE via LDS staging ----------
#define P2_T 512
#define CSR_CAP 6656   // avg 5120, +21 sigma headroom; 53 KB LDS
__global__ void k_csr(const int* __restrict__ bbase,
                      int2* __restrict__ ebuf,          // in: bucketed; out: CSR
                      int* __restrict__ row_ptr) {
    __shared__ int2 se[CSR_CAP];
    __shared__ int cnt[256];
    __shared__ int sc[256];
    __shared__ int pre[256];
    int b   = blockIdx.x;
    int beg = bbase[b], end = bbase[b + 1];
    int n   = end - beg;
    if (n > CSR_CAP) n = CSR_CAP;               // unreachable for this input
    for (int j = threadIdx.x; j < n; j += P2_T) se[j] = ebuf[beg + j];
    if (threadIdx.x < 256) cnt[threadIdx.x] = 0;
    __syncthreads();
    for (int j = threadIdx.x; j < n; j += P2_T)
        atomicAdd(&cnt[((unsigned)se[j].x) >> 18], 1);
    __syncthreads();
    if (threadIdx.x < 256) sc[threadIdx.x] = cnt[threadIdx.x];
    __syncthreads();
    for (int off = 1; off < 256; off <<= 1) {
        int v = 0;
        if (threadIdx.x < 256 && threadIdx.x >= off) v = sc[threadIdx.x - off];
        __syncthreads();
        if (threadIdx.x < 256) sc[threadIdx.x] += v;
        __syncthreads();
    }
    if (threadIdx.x < 256) {
        pre[threadIdx.x] = sc[threadIdx.x] - cnt[threadIdx.x];   // exclusive
        int row = b * 256 + threadIdx.x;
        if (row < NROWS) row_ptr[row] = beg + pre[threadIdx.x];
        cnt[threadIdx.x] = 0;                                    // reuse as fill
    }
    if (b == NB - 1 && threadIdx.x == 0) row_ptr[NROWS] = NNZ;
    __syncthreads();
    for (int j = threadIdx.x; j < n; j += P2_T) {
        int2 e  = se[j];
        int rlo = ((unsigned)e.x) >> 18;
        int col = e.x & 0x3FFFF;
        int rank = atomicAdd(&cnt[rlo], 1);
        ebuf[beg + pre[rlo] + rank] = make_int2(col, e.y);
    }
}

// ---------- bf16 helpers ----------
__device__ __forceinline__ float bfw_lo(unsigned int w) {   // elems at even pos
    return __uint_as_float(w << 16);
}
__device__ __forceinline__ float bfw_hi(unsigned int w) {   // elems at odd pos
    return __uint_as_float(w & 0xFFFF0000u);
}
__device__ __forceinline__ unsigned short f2bf(float f) {
    unsigned int b = __float_as_uint(f);
    return (unsigned short)((b + 0x7FFFu + ((b >> 16) & 1u)) >> 16);  // RN-even
}
__device__ __forceinline__ unsigned int pack2bf(float lo, float hi) {
    return (unsigned int)f2bf(lo) | ((unsigned int)f2bf(hi) << 16);
}

// xb = bf16(concat(user,item))
__global__ void k_cvt(const float4* __restrict__ user_emb,
                      const float4* __restrict__ item_emb,
                      ushort4* __restrict__ xb, int n4, int u4) {
    int i = blockIdx.x * blockDim.x + threadIdx.x;
    if (i < n4) {
        float4 v = (i < u4) ? user_emb[i] : item_emb[i - u4];
        xb[i] = make_ushort4(f2bf(v.x), f2bf(v.y), f2bf(v.z), f2bf(v.w));
    }
}

// ---------- gather SpMM: 8 lanes/row, 16B/lane, unroll x4 ----------
// Lane l holds dims [8l, 8l+8). 32 independent gathers in flight per wave.
// FIRST: acc = concat_f32 + s. FINAL: acc = (acc+s)*0.25, no y store.
template <int FIRST, int FINAL>
__global__ void k_spmm(const int* __restrict__ row_ptr,
                       const int2* __restrict__ csr,
                       const unsigned short* __restrict__ xb_in,
                       uint4* __restrict__ yb_out,           // ushort8 units
                       float4* __restrict__ acc,
                       const float4* __restrict__ user_emb,
                       const float4* __restrict__ item_emb) {
    int tid  = blockIdx.x * blockDim.x + threadIdx.x;
    int row  = tid >> 3;
    int lane = tid & 7;
    if (row >= NROWS) return;
    int beg = row_ptr[row];
    int end = row_ptr[row + 1];
    float s[4][8];
#pragma unroll
    for (int k = 0; k < 4; ++k)
#pragma unroll
        for (int d = 0; d < 8; ++d) s[k][d] = 0.f;

    const unsigned short* xlane = xb_in + lane * 8;
    int j = beg;
    int jend4 = beg + ((end - beg) & ~3);
    for (; j < jend4; j += 4) {
        int2 e[4];
#pragma unroll
        for (int k = 0; k < 4; ++k) e[k] = csr[j + k];
        uint4 u[4];
#pragma unroll
        for (int k = 0; k < 4; ++k)
            u[k] = *(const uint4*)(xlane + (size_t)e[k].x * D);
#pragma unroll
        for (int k = 0; k < 4; ++k) {
            float v = __int_as_float(e[k].y);
            s[k][0] += v * bfw_lo(u[k].x);
            s[k][1] += v * bfw_hi(u[k].x);
            s[k][2] += v * bfw_lo(u[k].y);
            s[k][3] += v * bfw_hi(u[k].y);
            s[k][4] += v * bfw_lo(u[k].z);
            s[k][5] += v * bfw_hi(u[k].z);
            s[k][6] += v * bfw_lo(u[k].w);
            s[k][7] += v * bfw_hi(u[k].w);
        }
    }
    for (; j < end; ++j) {
        int2 e = csr[j];
        float v = __int_as_float(e.y);
        uint4 u = *(const uint4*)(xlane + (size_t)e.x * D);
        s[0][0] += v * bfw_lo(u.x);
        s[0][1] += v * bfw_hi(u.x);
        s[0][2] += v * bfw_lo(u.y);
        s[0][3] += v * bfw_hi(u.y);
        s[0][4] += v * bfw_lo(u.z);
        s[0][5] += v * bfw_hi(u.z);
        s[0][6] += v * bfw_lo(u.w);
        s[0][7] += v * bfw_hi(u.w);
    }
    float r[8];
#pragma unroll
    for (int d = 0; d < 8; ++d)
        r[d] = (s[0][d] + s[1][d]) + (s[2][d] + s[3][d]);

    int o8 = row * 8 + lane;          // ushort8 index
    if (!FINAL) {
        uint4 y;
        y.x = pack2bf(r[0], r[1]);
        y.y = pack2bf(r[2], r[3]);
        y.z = pack2bf(r[4], r[5]);
        y.w = pack2bf(r[6], r[7]);
        yb_out[o8] = y;
    }
    int o4 = o8 * 2;                  // float4 index (two per lane)
    float4 a0, a1;
    if (FIRST) {
        if (row < U_ROWS) { a0 = user_emb[o4]; a1 = user_emb[o4 + 1]; }
        else { a0 = item_emb[o4 - U_ROWS * 16]; a1 = item_emb[o4 + 1 - U_ROWS * 16]; }
    } else {
        a0 = acc[o4]; a1 = acc[o4 + 1];
    }
    a0.x += r[0]; a0.y += r[1]; a0.z += r[2]; a0.w += r[3];
    a1.x += r[4]; a1.y += r[5]; a1.z += r[6]; a1.w += r[7];
    if (FINAL) {
        a0.x *= 0.25f; a0.y *= 0.25f; a0.z *= 0.25f; a0.w *= 0.25f;
        a1.x *= 0.25f; a1.y *= 0.25f; a1.z *= 0.25f; a1.w *= 0.25f;
    }
    acc[o4] = a0; acc[o4 + 1] = a1;
}

extern "C" void kernel_launch(void* const* d_in, const int* in_sizes, int n_in,
                              void* d_out, int out_size, void* d_ws, size_t ws_size,
                              hipStream_t stream) {
    const float* user_emb = (const float*)d_in[0];
    const float* item_emb = (const float*)d_in[1];
    const float* adj_vals = (const float*)d_in[2];
    const int*   adj_rows = (const int*)d_in[3];
    const int*   adj_cols = (const int*)d_in[4];

    // ---- ws layout (~62.6 MB total) ----
    char* w = (char*)d_ws;
    int*  row_ptr = (int*)w;   w += (((NROWS + 1) * 4) + 63) & ~63ul;
    int*  bcnt    = (int*)w;   w += ((NB * 4) + 63) & ~63ul;
    int*  bbase   = (int*)w;   w += (((NB + 1) * 4) + 63) & ~63ul;
    int*  bfill   = (int*)w;   w += ((NB * 4) + 63) & ~63ul;
    int2* ebuf    = (int2*)w;  w += (size_t)NNZ * 8;          // becomes CSR in-place
    unsigned short* xb0 = (unsigned short*)w;  w += (size_t)NROWS * D * 2;
    unsigned short* xb1 = (unsigned short*)w;
    float* acc = (float*)d_out;

    const int TB = 256;
    const int n4 = NROWS * D / 4;
    const int u4 = U_ROWS * D / 4;
    const int partBlocks = (NNZ + P1B_T * P1B_E - 1) / (P1B_T * P1B_E);  // 733
    const int spmmBlocks = (NROWS * 8 + TB - 1) / TB;                    // 4688

    // CSR build: bucket hist -> scan -> partition -> per-bucket in-place CSR
    hipMemsetAsync(bcnt, 0, NB * 4, stream);
    k_bhist<<<512, 256, 0, stream>>>(adj_rows, bcnt);
    k_bscan<<<1, 1024, 0, stream>>>(bcnt, bbase, bfill);
    k_part<<<partBlocks, P1B_T, 0, stream>>>(adj_rows, adj_cols, adj_vals, bfill, ebuf);
    k_csr<<<NB, P2_T, 0, stream>>>(bbase, ebuf, row_ptr);

    // bf16 ego0
    k_cvt<<<(n4 + TB - 1) / TB, TB, 0, stream>>>(
        (const float4*)user_emb, (const float4*)item_emb, (ushort4*)xb0, n4, u4);

    // 3 layers; acc init fused into layer 1, /4 fused into layer 3
    k_spmm<1, 0><<<spmmBlocks, TB, 0, stream>>>(row_ptr, ebuf, xb0, (uint4*)xb1,
        (float4*)acc, (const float4*)user_emb, (const float4*)item_emb);
    k_spmm<0, 0><<<spmmBlocks, TB, 0, stream>>>(row_ptr, ebuf, xb1, (uint4*)xb0,
        (float4*)acc, (const float4*)user_emb, (const float4*)item_emb);
    k_spmm<0, 1><<<spmmBlocks, TB, 0, stream>>>(row_ptr, ebuf, xb0, (uint4*)xb1,
        (float4*)acc, (const float4*)user_emb, (const float4*)item_emb);
}